// Round 15
// baseline (206.878 us; speedup 1.0000x reference)
//
#include <hip/hip_runtime.h>

typedef __attribute__((ext_vector_type(4))) float f32x4;
typedef __attribute__((ext_vector_type(8))) short short8;
typedef __attribute__((ext_vector_type(4))) unsigned short ushort4v;
typedef __attribute__((ext_vector_type(8))) unsigned short ushort8v;
typedef __attribute__((ext_vector_type(8))) _Float16 h16x8;

#define B_ROWS 4096
#define I_DIM  1024
#define O_DIM  1024
#define C_DIM  128
#define E_NUM  8

__device__ __forceinline__ float bfu2f(unsigned short u) {
  return __uint_as_float(((unsigned int)u) << 16);
}
__device__ __forceinline__ unsigned short f2bf(float f) {
  unsigned int u = __float_as_uint(f);
  unsigned int r = (u + 0x7FFFu + ((u >> 16) & 1u)) >> 16;  // RNE
  return (unsigned short)r;
}
__device__ __forceinline__ float ldany(const void* p, size_t idx, bool isbf) {
  return isbf ? bfu2f(((const unsigned short*)p)[idx]) : ((const float*)p)[idx];
}
__device__ __forceinline__ void gload_lds16(const void* g, void* lds) {
  __builtin_amdgcn_global_load_lds(
      (const __attribute__((address_space(1))) void*)g,
      (__attribute__((address_space(3))) void*)lds, 16, 0, 0);
}

// ---------------- dtype detect (ONE block — measured cheap in R7/R9) --------
__global__ void k_detect(const unsigned short* __restrict__ x, int* __restrict__ flag) {
  __shared__ int s[128];
  const int t = threadIdx.x;  // 128 threads
  const unsigned short v = x[t];
  const int ex = (v >> 7) & 0xFF;
  s[t] = (v == 0 || (ex >= 100 && ex <= 132)) ? 1 : 0;
  __syncthreads();
  if (t == 0) {
    int c = 0;
    for (int k = 0; k < 128; ++k) c += s[k];
    *flag = (c >= 120) ? 1 : 0;  // bf16 stream ~128/128 sane; f32 ~72/128
  }
}

// ---------------- fused prep: cast_x | transpose_w | gating (flag-based) ----
__global__ __launch_bounds__(256) void k_prep(
    const void* __restrict__ x, const void* __restrict__ cond,
    const void* __restrict__ wv, const void* __restrict__ w1,
    const void* __restrict__ b1, const void* __restrict__ w2,
    const void* __restrict__ b2, const int* __restrict__ flag,
    unsigned short* __restrict__ xb, unsigned short* __restrict__ wt,
    float* __restrict__ g)
{
  __shared__ float sm[4400];
  const bool isbf = (*flag != 0);
  const int tid = threadIdx.x;
  const int bid = blockIdx.x;

  if (bid < 2048) {                     // ---- cast x (f32 path only) ----
    if (isbf) return;                   // GEMM reads x directly
    const size_t i = ((size_t)bid * 256 + tid) * 8;
    const float* xf = (const float*)x;
    f32x4 a = *(const f32x4*)&xf[i];
    f32x4 b = *(const f32x4*)&xf[i + 4];
    ushort8v p;
#pragma unroll
    for (int j = 0; j < 4; ++j) { p[j] = f2bf(a[j]); p[j + 4] = f2bf(b[j]); }
    *(ushort8v*)&xb[i] = p;
  } else if (bid < 4096) {              // ---- transpose W ----
    float (*tile)[65] = (float(*)[65])sm;
    const int ta = bid - 2048;
    const int e = ta >> 8;
    const int t = ta & 255;
    const int i0 = (t >> 4) << 6;
    const int o0 = (t & 15) << 6;
    const size_t base = (size_t)e << 20;
    const int r = tid >> 2;
    const int sub = tid & 3;
    if (isbf) {
      const unsigned short* wu = (const unsigned short*)wv;
#pragma unroll
      for (int q = 0; q < 2; ++q) {     // 2 x 16B loads
        const int c = sub * 16 + q * 8;
        ushort8v v = *(const ushort8v*)&wu[base + (size_t)(i0 + r) * O_DIM + o0 + c];
#pragma unroll
        for (int j = 0; j < 8; ++j) tile[r][c + j] = bfu2f(v[j]);
      }
    } else {
      const float* wf = (const float*)wv;
#pragma unroll
      for (int q = 0; q < 4; ++q) {
        const int c = sub * 16 + q * 4;
        f32x4 v = *(const f32x4*)&wf[base + (size_t)(i0 + r) * O_DIM + o0 + c];
#pragma unroll
        for (int j = 0; j < 4; ++j) tile[r][c + j] = v[j];
      }
    }
    __syncthreads();
    // store: 4 threads per o-row, 32B each -> 128B contiguous per row
    const int oc = tid >> 2;
    const int iq = (tid & 3) * 16;
    ushort8v p0, p1;
#pragma unroll
    for (int j = 0; j < 8; ++j) p0[j] = f2bf(tile[iq + j][oc]);
#pragma unroll
    for (int j = 0; j < 8; ++j) p1[j] = f2bf(tile[iq + 8 + j][oc]);
    unsigned short* dst = &wt[base + (size_t)(o0 + oc) * I_DIM + i0 + iq];
    *(ushort8v*)dst = p0;
    *(ushort8v*)(dst + 8) = p1;
  } else {                              // ---- gating ----
    float* s_w1 = sm;            // 4096
    float* s_w2 = sm + 4096;     // 256
    float* s_b1 = sm + 4352;     // 32
    float* s_b2 = sm + 4384;     // 8
    for (int t = tid; t < C_DIM * 32; t += 256) s_w1[t] = ldany(w1, t, isbf);
    if (tid < 32 * E_NUM) s_w2[tid] = ldany(w2, tid, isbf);
    if (tid < 32) s_b1[tid] = ldany(b1, tid, isbf);
    if (tid < E_NUM) s_b2[tid] = ldany(b2, tid, isbf);
    __syncthreads();
    const int b = (bid - 4096) * 256 + tid;
    float h[32];
#pragma unroll
    for (int j = 0; j < 32; ++j) h[j] = s_b1[j];
    for (int i = 0; i < C_DIM; i += 8) {
      float c[8];
      if (isbf) {
        const unsigned short* cu = (const unsigned short*)cond;
        ushort8v v = *(const ushort8v*)&cu[(size_t)b * C_DIM + i];
#pragma unroll
        for (int q = 0; q < 8; ++q) c[q] = bfu2f(v[q]);
      } else {
        const float* cf = (const float*)cond;
        f32x4 v0 = *(const f32x4*)&cf[(size_t)b * C_DIM + i];
        f32x4 v1 = *(const f32x4*)&cf[(size_t)b * C_DIM + i + 4];
#pragma unroll
        for (int q = 0; q < 4; ++q) { c[q] = v0[q]; c[q + 4] = v1[q]; }
      }
#pragma unroll
      for (int q = 0; q < 8; ++q)
#pragma unroll
        for (int j = 0; j < 32; ++j)
          h[j] = fmaf(c[q], s_w1[(i + q) * 32 + j], h[j]);
    }
#pragma unroll
    for (int j = 0; j < 32; ++j) h[j] = fmaxf(h[j], 0.f);
    float lg[E_NUM];
#pragma unroll
    for (int e = 0; e < E_NUM; ++e) lg[e] = s_b2[e];
#pragma unroll
    for (int j = 0; j < 32; ++j)
#pragma unroll
      for (int e = 0; e < E_NUM; ++e)
        lg[e] = fmaf(h[j], s_w2[j * E_NUM + e], lg[e]);
    float mx = lg[0];
#pragma unroll
    for (int e = 1; e < E_NUM; ++e) mx = fmaxf(mx, lg[e]);
    float s = 0.f;
#pragma unroll
    for (int e = 0; e < E_NUM; ++e) { lg[e] = expf(lg[e] - mx); s += lg[e]; }
    const float inv = 1.f / s;
#pragma unroll
    for (int e = 0; e < E_NUM; ++e) g[(size_t)b * E_NUM + e] = lg[e] * inv;
  }
}

// ---------------- main GEMM: m97-faithful 128x128, 4 waves, 2-barrier -------
// The guide's measured tile-space AT THE SIMPLE STRUCTURE: 128^2 = 912 TF
// (vs 256^2 = 792) — via ~3 co-resident blocks/CU absorbing barrier stalls
// (m114). NO asm waits, NO sched_barriers, NO ring-3: one __syncthreads per
// K-tile (compiler emits vmcnt(0)+lgkmcnt(0) drain before s_barrier), next
// tile's global_load_lds issued right after the barrier so it flies across
// the MFMA block and is drained at the NEXT barrier. dbuf-2, BK=32, wave
// tile 64x64 (acc 64 regs, frags 32, single-buffered — compiler schedules
// lgkm counted waits). LDS 36KB. Chunk layout [kslot4][row16][8bf16]: frag
// reads and gload dests both linear in lane (conflict-free, R5-verified).
// KS=4 expert-split, grid 1024 (4-deep/CU). A-source selected by flag.
#define BM 128
#define BN 128
#define BK 32
#define MT (B_ROWS / BM)   // 32
#define NT (O_DIM / BN)    // 8

__global__ __launch_bounds__(256) void k_moe_gemm(
    const void* __restrict__ xv, const unsigned short* __restrict__ xb,
    const unsigned short* __restrict__ wt, const float* __restrict__ g,
    const int* __restrict__ flag, _Float16* __restrict__ pbuf, int EPB)
{
  __shared__ unsigned short As[2][BM * BK];  // 2 x 8KB
  __shared__ unsigned short Bs[2][BN * BK];  // 2 x 8KB
  __shared__ float gsh[BM * E_NUM];          // 4KB (36KB total)

  const int tid  = threadIdx.x;
  const int lane = tid & 63;
  const int w    = tid >> 6;      // wave 0..3
  const int wr   = w >> 1;        // 0..1 (64 rows)
  const int wc   = w & 1;         // 0..1 (64 cols)

  const unsigned short* xsrc = (*flag != 0) ? (const unsigned short*)xv : xb;

  // bijective XCD swizzle (nwg = KS*256, % 8 == 0)
  const int nwg = gridDim.x;
  const int cpx = nwg >> 3;
  const int wg  = ((int)blockIdx.x & 7) * cpx + ((int)blockIdx.x >> 3);
  const int ks  = wg >> 8;            // split-K slice
  const int t2  = wg & 255;
  const int mt  = t2 >> 3;
  const int nt  = t2 & 7;
  const int row0 = mt * BM;
  const int col0 = nt * BN;
  const int NKT  = EPB << 5;          // K-tiles of 32 (pow2)
  const int e0   = ks * EPB;

  for (int i = tid; i < BM * E_NUM; i += 256) gsh[i] = g[row0 * E_NUM + i];

  // staging: wave w stages A rows [32w,32w+32) AND B cols [32w,32w+32)
  // (2 chunks each, 16 rows x 32 k per 1KB chunk). lane l -> row l&15,
  // kslot l>>4 -> LDS dest lane*16 linear.
  const int lr = lane & 15;
  const int lk = lane >> 4;
  const unsigned short* aS0 = xsrc + (size_t)(row0 + w * 32 + lr) * I_DIM + lk * 8;
  const unsigned short* aS1 = aS0 + (size_t)16 * I_DIM;
  const unsigned short* bS0 = wt + (size_t)(col0 + w * 32 + lr) * I_DIM + lk * 8;
  const unsigned short* bS1 = bS0 + (size_t)16 * I_DIM;
  const int dA0 = (w * 2 + 0) * 512, dA1 = (w * 2 + 1) * 512;  // ushort offs

#define STAGE(buf, kt) do { \
    const size_t eb_ = (size_t)(e0 + ((kt) >> 5)) << 20; \
    const int ko_ = ((kt) & 31) << 5; \
    unsigned short* As_ = (unsigned short*)&As[buf][0]; \
    unsigned short* Bs_ = (unsigned short*)&Bs[buf][0]; \
    gload_lds16(aS0 + ko_, As_ + dA0); \
    gload_lds16(aS1 + ko_, As_ + dA1); \
    gload_lds16(bS0 + eb_ + ko_, Bs_ + dA0); \
    gload_lds16(bS1 + eb_ + ko_, Bs_ + dA1); } while (0)

  const int fro = lane * 8;

#define READ_FRAGS(fa, fb, buf) do { \
    const unsigned short* Ar_ = &As[buf][0]; \
    const unsigned short* Br_ = &Bs[buf][0]; \
    _Pragma("unroll") for (int n_ = 0; n_ < 4; ++n_) \
      fb[n_] = *(const short8*)&Br_[(wc * 4 + n_) * 512 + fro]; \
    _Pragma("unroll") for (int m_ = 0; m_ < 4; ++m_) \
      fa[m_] = *(const short8*)&Ar_[(wr * 4 + m_) * 512 + fro]; } while (0)

#define MFMA_ALL(fa, fb) do { \
    _Pragma("unroll") for (int m_ = 0; m_ < 4; ++m_) \
      _Pragma("unroll") for (int n_ = 0; n_ < 4; ++n_) \
        acc[m_][n_] = __builtin_amdgcn_mfma_f32_16x16x32_bf16(fa[m_], fb[n_], acc[m_][n_], 0, 0, 0); \
    } while (0)

  const int r16  = lane & 15;     // C/D col within 16
  const int krow = lane >> 4;     // C/D row group

#define RESCALE(en) do { \
    _Pragma("unroll") for (int m_ = 0; m_ < 4; ++m_) { \
      const int rowl_ = wr * 64 + m_ * 16 + krow * 4; \
      float ra_[4]; \
      _Pragma("unroll") for (int r_ = 0; r_ < 4; ++r_) \
        ra_[r_] = fmaxf(gsh[(rowl_ + r_) * E_NUM + (en) - 1], 1e-30f) / \
                  fmaxf(gsh[(rowl_ + r_) * E_NUM + (en)], 1e-30f); \
      _Pragma("unroll") for (int n_ = 0; n_ < 4; ++n_) \
        _Pragma("unroll") for (int r_ = 0; r_ < 4; ++r_) \
          acc[m_][n_][r_] *= ra_[r_]; } } while (0)

  f32x4 acc[4][4];
#pragma unroll
  for (int m = 0; m < 4; ++m)
#pragma unroll
    for (int n = 0; n < 4; ++n)
#pragma unroll
      for (int r2 = 0; r2 < 4; ++r2) acc[m][n][r2] = 0.f;

  short8 a[4], b[4];

  // prologue: stage tile 0 into buf 0
  STAGE(0, 0);

  for (int t = 0; t < NKT; ++t) {
    __syncthreads();   // compiler drains vmcnt(0)+lgkmcnt(0): buf[t&1] ready,
                       // all waves' reads of tile t-1 complete
    if (t + 1 < NKT) STAGE((t + 1) & 1, t + 1);  // in flight across MFMA
    if (EPB > 1 && t && !(t & 31)) RESCALE(e0 + (t >> 5));
    READ_FRAGS(a, b, t & 1);
    MFMA_ALL(a, b);
  }
#undef STAGE
#undef READ_FRAGS
#undef MFMA_ALL
#undef RESCALE

  // epilogue: final gate scale, write f16 partial (bias in combine)
  const int elast = e0 + EPB - 1;
  _Float16* pb = pbuf + ((size_t)ks << 22);
#pragma unroll
  for (int m = 0; m < 4; ++m) {
    const int rowl = wr * 64 + m * 16 + krow * 4;
    float gl[4];
#pragma unroll
    for (int r2 = 0; r2 < 4; ++r2)
      gl[r2] = fmaxf(gsh[(rowl + r2) * E_NUM + elast], 1e-30f);
#pragma unroll
    for (int n = 0; n < 4; ++n) {
      const int c = col0 + wc * 64 + n * 16 + r16;
#pragma unroll
      for (int r2 = 0; r2 < 4; ++r2)
        pb[(size_t)(row0 + rowl + r2) * O_DIM + c] =
            (_Float16)(acc[m][n][r2] * gl[r2]);
    }
  }
}

// ---------------- combine: sum f16 slabs + VECTORIZED bias, cast ------------
__global__ __launch_bounds__(256) void k_combine(
    const _Float16* __restrict__ pbuf, const float* __restrict__ g,
    const void* __restrict__ biasv, const int* __restrict__ flag,
    void* __restrict__ outv, int KS)
{
  const bool isbf = (*flag != 0);
  const int idx = blockIdx.x * 256 + threadIdx.x;
  const int b = idx >> 7;
  const int o = (idx & 127) << 3;
  float s[8];
#pragma unroll
  for (int j = 0; j < 8; ++j) s[j] = 0.f;
  for (int ks = 0; ks < KS; ++ks) {
    h16x8 v = *(const h16x8*)&pbuf[((size_t)ks << 22) + (size_t)b * O_DIM + o];
#pragma unroll
    for (int j = 0; j < 8; ++j) s[j] += (float)v[j];
  }
  // bias term: sum_e g[b,e] * bias[e, o..o+7], vector loads per e
  f32x4 g0 = *(const f32x4*)&g[(size_t)b * E_NUM];
  f32x4 g1 = *(const f32x4*)&g[(size_t)b * E_NUM + 4];
  float gr[E_NUM];
#pragma unroll
  for (int e = 0; e < 4; ++e) { gr[e] = g0[e]; gr[e + 4] = g1[e]; }
  if (isbf) {
    const unsigned short* bu = (const unsigned short*)biasv;
#pragma unroll
    for (int e = 0; e < E_NUM; ++e) {
      ushort8v bv = *(const ushort8v*)&bu[(size_t)e * O_DIM + o];
#pragma unroll
      for (int j = 0; j < 8; ++j) s[j] += gr[e] * bfu2f(bv[j]);
    }
  } else {
    const float* bf_ = (const float*)biasv;
#pragma unroll
    for (int e = 0; e < E_NUM; ++e) {
      f32x4 lo = *(const f32x4*)&bf_[(size_t)e * O_DIM + o];
      f32x4 hi = *(const f32x4*)&bf_[(size_t)e * O_DIM + o + 4];
#pragma unroll
      for (int j = 0; j < 4; ++j) {
        s[j]     += gr[e] * lo[j];
        s[j + 4] += gr[e] * hi[j];
      }
    }
  }
  if (isbf) {
    ushort8v pk;
#pragma unroll
    for (int j = 0; j < 8; ++j) pk[j] = f2bf(s[j]);
    *(ushort8v*)&((unsigned short*)outv)[(size_t)b * O_DIM + o] = pk;
  } else {
    float* of = (float*)outv + (size_t)b * O_DIM + o;
    f32x4 lo, hi;
#pragma unroll
    for (int j = 0; j < 4; ++j) { lo[j] = s[j]; hi[j] = s[j + 4]; }
    *(f32x4*)of = lo;
    *(f32x4*)(of + 4) = hi;
  }
}

extern "C" void kernel_launch(void* const* d_in, const int* in_sizes, int n_in,
                              void* d_out, int out_size, void* d_ws, size_t ws_size,
                              hipStream_t stream) {
  (void)in_sizes; (void)n_in; (void)out_size;
  const void* x    = d_in[0];
  const void* cond = d_in[1];
  const void* w    = d_in[2];
  const void* bias = d_in[3];
  const void* g_w1 = d_in[4];
  const void* g_b1 = d_in[5];
  const void* g_w2 = d_in[6];
  const void* g_b2 = d_in[7];

  const size_t goff  = 1024;
  const size_t wtoff = goff + (size_t)B_ROWS * E_NUM * 4;         // +128KB
  const size_t xboff = wtoff + (size_t)E_NUM * I_DIM * O_DIM * 2; // +16MB
  const size_t poff  = xboff + (size_t)B_ROWS * I_DIM * 2;        // +8MB
  const size_t slab  = (size_t)B_ROWS * O_DIM * 2;                // 8MB (f16)

  int KS = 4;
  while (KS > 1 && poff + (size_t)KS * slab > ws_size) KS >>= 1;
  const int EPB = E_NUM / KS;

  int*   flag = (int*)d_ws;
  float* g    = (float*)((char*)d_ws + goff);
  unsigned short* wt = (unsigned short*)((char*)d_ws + wtoff);
  unsigned short* xbb = (unsigned short*)((char*)d_ws + xboff);
  _Float16* pbuf = (_Float16*)((char*)d_ws + poff);

  k_detect<<<1, 128, 0, stream>>>((const unsigned short*)x, flag);
  k_prep<<<4112, 256, 0, stream>>>(x, cond, w, g_w1, g_b1, g_w2, g_b2, flag,
                                   xbb, wt, g);
  k_moe_gemm<<<KS * MT * NT, 256, 0, stream>>>(x, xbb, wt, g, flag, pbuf, EPB);
  k_combine<<<B_ROWS * O_DIM / 8 / 256, 256, 0, stream>>>(pbuf, g, bias, flag,
                                                          d_out, KS);
}

// Round 16
// 127.769 us; speedup vs baseline: 1.6192x; 1.6192x over previous
//
#include <hip/hip_runtime.h>

typedef __attribute__((ext_vector_type(4))) float f32x4;
typedef __attribute__((ext_vector_type(8))) short short8;
typedef __attribute__((ext_vector_type(4))) unsigned short ushort4v;
typedef __attribute__((ext_vector_type(8))) unsigned short ushort8v;
typedef __attribute__((ext_vector_type(8))) _Float16 h16x8;

#define B_ROWS 4096
#define I_DIM  1024
#define O_DIM  1024
#define C_DIM  128
#define E_NUM  8

__device__ __forceinline__ float bfu2f(unsigned short u) {
  return __uint_as_float(((unsigned int)u) << 16);
}
__device__ __forceinline__ unsigned short f2bf(float f) {
  unsigned int u = __float_as_uint(f);
  unsigned int r = (u + 0x7FFFu + ((u >> 16) & 1u)) >> 16;  // RNE
  return (unsigned short)r;
}
__device__ __forceinline__ float ldany(const void* p, size_t idx, bool isbf) {
  return isbf ? bfu2f(((const unsigned short*)p)[idx]) : ((const float*)p)[idx];
}
__device__ __forceinline__ void gload_lds16(const void* g, void* lds) {
  __builtin_amdgcn_global_load_lds(
      (const __attribute__((address_space(1))) void*)g,
      (__attribute__((address_space(3))) void*)lds, 16, 0, 0);
}

// ---------------- dtype detect (ONE block — measured cheap in R7/R9) --------
__global__ void k_detect(const unsigned short* __restrict__ x, int* __restrict__ flag) {
  __shared__ int s[128];
  const int t = threadIdx.x;  // 128 threads
  const unsigned short v = x[t];
  const int ex = (v >> 7) & 0xFF;
  s[t] = (v == 0 || (ex >= 100 && ex <= 132)) ? 1 : 0;
  __syncthreads();
  if (t == 0) {
    int c = 0;
    for (int k = 0; k < 128; ++k) c += s[k];
    *flag = (c >= 120) ? 1 : 0;  // bf16 stream ~128/128 sane; f32 ~72/128
  }
}

// ---------------- fused prep: cast_x | transpose_w | gating (flag-based) ----
__global__ __launch_bounds__(256) void k_prep(
    const void* __restrict__ x, const void* __restrict__ cond,
    const void* __restrict__ wv, const void* __restrict__ w1,
    const void* __restrict__ b1, const void* __restrict__ w2,
    const void* __restrict__ b2, const int* __restrict__ flag,
    unsigned short* __restrict__ xb, unsigned short* __restrict__ wt,
    float* __restrict__ g)
{
  __shared__ float sm[4400];
  const bool isbf = (*flag != 0);
  const int tid = threadIdx.x;
  const int bid = blockIdx.x;

  if (bid < 2048) {                     // ---- cast x (f32 path only) ----
    if (isbf) return;                   // GEMM reads x directly
    const size_t i = ((size_t)bid * 256 + tid) * 8;
    const float* xf = (const float*)x;
    f32x4 a = *(const f32x4*)&xf[i];
    f32x4 b = *(const f32x4*)&xf[i + 4];
    ushort8v p;
#pragma unroll
    for (int j = 0; j < 4; ++j) { p[j] = f2bf(a[j]); p[j + 4] = f2bf(b[j]); }
    *(ushort8v*)&xb[i] = p;
  } else if (bid < 4096) {              // ---- transpose W ----
    float (*tile)[65] = (float(*)[65])sm;
    const int ta = bid - 2048;
    const int e = ta >> 8;
    const int t = ta & 255;
    const int i0 = (t >> 4) << 6;
    const int o0 = (t & 15) << 6;
    const size_t base = (size_t)e << 20;
    const int r = tid >> 2;
    const int sub = tid & 3;
    if (isbf) {
      const unsigned short* wu = (const unsigned short*)wv;
#pragma unroll
      for (int q = 0; q < 2; ++q) {     // 2 x 16B loads
        const int c = sub * 16 + q * 8;
        ushort8v v = *(const ushort8v*)&wu[base + (size_t)(i0 + r) * O_DIM + o0 + c];
#pragma unroll
        for (int j = 0; j < 8; ++j) tile[r][c + j] = bfu2f(v[j]);
      }
    } else {
      const float* wf = (const float*)wv;
#pragma unroll
      for (int q = 0; q < 4; ++q) {
        const int c = sub * 16 + q * 4;
        f32x4 v = *(const f32x4*)&wf[base + (size_t)(i0 + r) * O_DIM + o0 + c];
#pragma unroll
        for (int j = 0; j < 4; ++j) tile[r][c + j] = v[j];
      }
    }
    __syncthreads();
    // store: 4 threads per o-row, 32B each -> 128B contiguous per row
    const int oc = tid >> 2;
    const int iq = (tid & 3) * 16;
    ushort8v p0, p1;
#pragma unroll
    for (int j = 0; j < 8; ++j) p0[j] = f2bf(tile[iq + j][oc]);
#pragma unroll
    for (int j = 0; j < 8; ++j) p1[j] = f2bf(tile[iq + 8 + j][oc]);
    unsigned short* dst = &wt[base + (size_t)(o0 + oc) * I_DIM + i0 + iq];
    *(ushort8v*)dst = p0;
    *(ushort8v*)(dst + 8) = p1;
  } else {                              // ---- gating ----
    float* s_w1 = sm;            // 4096
    float* s_w2 = sm + 4096;     // 256
    float* s_b1 = sm + 4352;     // 32
    float* s_b2 = sm + 4384;     // 8
    for (int t = tid; t < C_DIM * 32; t += 256) s_w1[t] = ldany(w1, t, isbf);
    if (tid < 32 * E_NUM) s_w2[tid] = ldany(w2, tid, isbf);
    if (tid < 32) s_b1[tid] = ldany(b1, tid, isbf);
    if (tid < E_NUM) s_b2[tid] = ldany(b2, tid, isbf);
    __syncthreads();
    const int b = (bid - 4096) * 256 + tid;
    float h[32];
#pragma unroll
    for (int j = 0; j < 32; ++j) h[j] = s_b1[j];
    for (int i = 0; i < C_DIM; i += 8) {
      float c[8];
      if (isbf) {
        const unsigned short* cu = (const unsigned short*)cond;
        ushort8v v = *(const ushort8v*)&cu[(size_t)b * C_DIM + i];
#pragma unroll
        for (int q = 0; q < 8; ++q) c[q] = bfu2f(v[q]);
      } else {
        const float* cf = (const float*)cond;
        f32x4 v0 = *(const f32x4*)&cf[(size_t)b * C_DIM + i];
        f32x4 v1 = *(const f32x4*)&cf[(size_t)b * C_DIM + i + 4];
#pragma unroll
        for (int q = 0; q < 4; ++q) { c[q] = v0[q]; c[q + 4] = v1[q]; }
      }
#pragma unroll
      for (int q = 0; q < 8; ++q)
#pragma unroll
        for (int j = 0; j < 32; ++j)
          h[j] = fmaf(c[q], s_w1[(i + q) * 32 + j], h[j]);
    }
#pragma unroll
    for (int j = 0; j < 32; ++j) h[j] = fmaxf(h[j], 0.f);
    float lg[E_NUM];
#pragma unroll
    for (int e = 0; e < E_NUM; ++e) lg[e] = s_b2[e];
#pragma unroll
    for (int j = 0; j < 32; ++j)
#pragma unroll
      for (int e = 0; e < E_NUM; ++e)
        lg[e] = fmaf(h[j], s_w2[j * E_NUM + e], lg[e]);
    float mx = lg[0];
#pragma unroll
    for (int e = 1; e < E_NUM; ++e) mx = fmaxf(mx, lg[e]);
    float s = 0.f;
#pragma unroll
    for (int e = 0; e < E_NUM; ++e) { lg[e] = expf(lg[e] - mx); s += lg[e]; }
    const float inv = 1.f / s;
#pragma unroll
    for (int e = 0; e < E_NUM; ++e) g[(size_t)b * E_NUM + e] = lg[e] * inv;
  }
}

// ---------------- main GEMM: R5-exact register-pipelined ring-3 -------------
// Measured 83.6-83.9us / MfmaUtil ~33.5% / conflicts 3.9e5 across R10-R14
// (stable, twice-reproduced best). 256x256 tile, BK=32, 8 waves (2M x 4N)
// each 128x64, KS=4 expert-split (grid 256 = 1 block/CU; 252 unified regs
// pin 8 waves/CU). Iteration t: read frags(t+1) (reg dbuf), stage(t+3)->
// slot t%3, MFMA frags(t), vmcnt(4), ONE barrier. Chunk LDS layout
// [kslot4][row16][8bf16]: frag reads and gload dests linear in lane.
// A-source selected by flag (x directly when bf16).
// Refuted alternatives (this session): 4-phase (-54%), read-ahead 1-barrier
// (-50%), launch_bounds occupancy (acc spill to scratch), 128^2 pipelined
// (-67%), 128^2 simple m97-style (-100%).
#define BM 256
#define BN 256
#define BK 32
#define MT (B_ROWS / BM)   // 16
#define NT (O_DIM / BN)    // 4

__global__ __launch_bounds__(512, 2) void k_moe_gemm(
    const void* __restrict__ xv, const unsigned short* __restrict__ xb,
    const unsigned short* __restrict__ wt, const float* __restrict__ g,
    const int* __restrict__ flag, _Float16* __restrict__ pbuf, int EPB)
{
  __shared__ unsigned short As[3][BM * BK];  // 3 x 16KB
  __shared__ unsigned short Bs[3][BN * BK];  // 3 x 16KB
  __shared__ float gsh[BM * E_NUM];          // 8KB (104KB total)

  const int tid  = threadIdx.x;
  const int lane = tid & 63;
  const int w    = tid >> 6;      // wave 0..7
  const int wr   = w >> 2;        // 0..1  (128 rows)
  const int wc   = w & 3;         // 0..3  (64 cols)

  // A source: x directly when already bf16 (identical layout), else xb copy
  const unsigned short* xsrc = (*flag != 0) ? (const unsigned short*)xv : xb;

  // bijective XCD swizzle (nwg = KS*64, % 8 == 0)
  const int nwg = gridDim.x;
  const int cpx = nwg >> 3;
  const int wg  = ((int)blockIdx.x & 7) * cpx + ((int)blockIdx.x >> 3);
  const int ks  = wg >> 6;            // split-K slice
  const int t2  = wg & 63;
  const int mt  = t2 >> 2;
  const int nt  = t2 & 3;
  const int row0 = mt * BM;
  const int col0 = nt * BN;
  const int NKT  = EPB << 5;          // K-tiles of 32 (pow2)
  const int e0   = ks * EPB;

  for (int i = tid; i < BM * E_NUM; i += 512) gsh[i] = g[row0 * E_NUM + i];

  // staging: wave w stages rows/cols [w*32, w*32+32) as chunks 2w, 2w+1.
  const int lr = lane & 15;
  const int lk = lane >> 4;
  const unsigned short* aS0 = xsrc + (size_t)(row0 + w * 32 + lr) * I_DIM + lk * 8;
  const unsigned short* aS1 = aS0 + (size_t)16 * I_DIM;
  const unsigned short* bS0 = wt + (size_t)(col0 + w * 32 + lr) * I_DIM + lk * 8;
  const unsigned short* bS1 = bS0 + (size_t)16 * I_DIM;
  const int dA0 = (w * 2 + 0) * 512, dA1 = (w * 2 + 1) * 512;  // ushort offs

#define STAGE(slot, ebase, koff) do { \
    unsigned short* As_ = (unsigned short*)&As[slot][0]; \
    unsigned short* Bs_ = (unsigned short*)&Bs[slot][0]; \
    gload_lds16(aS0 + (koff), As_ + dA0); \
    gload_lds16(aS1 + (koff), As_ + dA1); \
    gload_lds16(bS0 + (ebase) + (koff), Bs_ + dA0); \
    gload_lds16(bS1 + (ebase) + (koff), Bs_ + dA1); } while (0)

  const int fro = lane * 8;

#define READ_FRAGS(fa, fb, slot) do { \
    const unsigned short* Ar_ = &As[slot][0]; \
    const unsigned short* Br_ = &Bs[slot][0]; \
    _Pragma("unroll") for (int n_ = 0; n_ < 4; ++n_) \
      fb[n_] = *(const short8*)&Br_[(wc * 4 + n_) * 512 + fro]; \
    _Pragma("unroll") for (int m_ = 0; m_ < 8; ++m_) \
      fa[m_] = *(const short8*)&Ar_[(wr * 8 + m_) * 512 + fro]; } while (0)

#define MFMA_ALL(fa, fb) do { \
    __builtin_amdgcn_s_setprio(1); \
    _Pragma("unroll") for (int m_ = 0; m_ < 8; ++m_) \
      _Pragma("unroll") for (int n_ = 0; n_ < 4; ++n_) \
        acc[m_][n_] = __builtin_amdgcn_mfma_f32_16x16x32_bf16(fa[m_], fb[n_], acc[m_][n_], 0, 0, 0); \
    __builtin_amdgcn_s_setprio(0); } while (0)

  const int r16  = lane & 15;     // C/D col within 16
  const int krow = lane >> 4;     // C/D row group

#define RESCALE(en) do { \
    _Pragma("unroll") for (int m_ = 0; m_ < 8; ++m_) { \
      const int rowl_ = wr * 128 + m_ * 16 + krow * 4; \
      float ra_[4]; \
      _Pragma("unroll") for (int r_ = 0; r_ < 4; ++r_) \
        ra_[r_] = fmaxf(gsh[(rowl_ + r_) * E_NUM + (en) - 1], 1e-30f) / \
                  fmaxf(gsh[(rowl_ + r_) * E_NUM + (en)], 1e-30f); \
      _Pragma("unroll") for (int n_ = 0; n_ < 4; ++n_) \
        _Pragma("unroll") for (int r_ = 0; r_ < 4; ++r_) \
          acc[m_][n_][r_] *= ra_[r_]; } } while (0)

  f32x4 acc[8][4];
#pragma unroll
  for (int m = 0; m < 8; ++m)
#pragma unroll
    for (int n = 0; n < 4; ++n)
#pragma unroll
      for (int r2 = 0; r2 < 4; ++r2) acc[m][n][r2] = 0.f;

  short8 a0[8], b0[4], a1[8], b1[4];
  const size_t eb0 = (size_t)e0 << 20;

  // prologue: stage tiles 0,1 -> slots 0,1; read frags(0); stage tile 2.
  STAGE(0, eb0, 0);
  STAGE(1, eb0, BK);
  asm volatile("s_waitcnt vmcnt(4)" ::: "memory");   // stage0 done
  __builtin_amdgcn_sched_barrier(0);
  __builtin_amdgcn_s_barrier();
  READ_FRAGS(a0, b0, 0);
  __builtin_amdgcn_sched_barrier(0);
  STAGE(2, eb0, 2 * BK);
  asm volatile("s_waitcnt vmcnt(4)" ::: "memory");   // stage1 done
  __builtin_amdgcn_sched_barrier(0);
  __builtin_amdgcn_s_barrier();

  int srd = 1;  // slot of tile t+1
  int sst = 0;  // slot for tile t+3
  for (int t = 0; t < NKT; t += 2) {
    // ---- even half: read frags(t+1), stage(t+3), MFMA frags(t) ----
    if (t > 0 && (t & 31) == 0) RESCALE(e0 + (t >> 5));
    READ_FRAGS(a1, b1, srd);
    __builtin_amdgcn_sched_barrier(0);
    {
      const int kst = (t + 3) & (NKT - 1);
      STAGE(sst, (size_t)(e0 + (kst >> 5)) << 20, (kst & 31) * BK);
    }
    __builtin_amdgcn_sched_barrier(0);
    MFMA_ALL(a0, b0);
    asm volatile("s_waitcnt vmcnt(4)" ::: "memory");
    __builtin_amdgcn_sched_barrier(0);
    __builtin_amdgcn_s_barrier();
    srd = (srd == 2) ? 0 : srd + 1;
    sst = (sst == 2) ? 0 : sst + 1;

    // ---- odd half: read frags(t+2), stage(t+4), MFMA frags(t+1) ----
    READ_FRAGS(a0, b0, srd);
    __builtin_amdgcn_sched_barrier(0);
    {
      const int kst = (t + 4) & (NKT - 1);
      STAGE(sst, (size_t)(e0 + (kst >> 5)) << 20, (kst & 31) * BK);
    }
    __builtin_amdgcn_sched_barrier(0);
    MFMA_ALL(a1, b1);
    asm volatile("s_waitcnt vmcnt(4)" ::: "memory");
    __builtin_amdgcn_sched_barrier(0);
    __builtin_amdgcn_s_barrier();
    srd = (srd == 2) ? 0 : srd + 1;
    sst = (sst == 2) ? 0 : sst + 1;
  }
#undef STAGE
#undef READ_FRAGS
#undef MFMA_ALL
#undef RESCALE

  // epilogue: drain, final gate scale, write f16 partial (bias in combine)
  asm volatile("s_waitcnt vmcnt(0) lgkmcnt(0)" ::: "memory");
  const int elast = e0 + EPB - 1;
  _Float16* pb = pbuf + ((size_t)ks << 22);
#pragma unroll
  for (int m = 0; m < 8; ++m) {
    const int rowl = wr * 128 + m * 16 + krow * 4;
    float gl[4];
#pragma unroll
    for (int r2 = 0; r2 < 4; ++r2)
      gl[r2] = fmaxf(gsh[(rowl + r2) * E_NUM + elast], 1e-30f);
#pragma unroll
    for (int n = 0; n < 4; ++n) {
      const int c = col0 + wc * 64 + n * 16 + r16;
#pragma unroll
      for (int r2 = 0; r2 < 4; ++r2)
        pb[(size_t)(row0 + rowl + r2) * O_DIM + c] =
            (_Float16)(acc[m][n][r2] * gl[r2]);
    }
  }
}

// ---------------- combine: sum f16 slabs + VECTORIZED bias, cast ------------
__global__ __launch_bounds__(256) void k_combine(
    const _Float16* __restrict__ pbuf, const float* __restrict__ g,
    const void* __restrict__ biasv, const int* __restrict__ flag,
    void* __restrict__ outv, int KS)
{
  const bool isbf = (*flag != 0);
  const int idx = blockIdx.x * 256 + threadIdx.x;
  const int b = idx >> 7;
  const int o = (idx & 127) << 3;
  float s[8];
#pragma unroll
  for (int j = 0; j < 8; ++j) s[j] = 0.f;
  for (int ks = 0; ks < KS; ++ks) {
    h16x8 v = *(const h16x8*)&pbuf[((size_t)ks << 22) + (size_t)b * O_DIM + o];
#pragma unroll
    for (int j = 0; j < 8; ++j) s[j] += (float)v[j];
  }
  // bias term: sum_e g[b,e] * bias[e, o..o+7], vector loads per e
  f32x4 g0 = *(const f32x4*)&g[(size_t)b * E_NUM];
  f32x4 g1 = *(const f32x4*)&g[(size_t)b * E_NUM + 4];
  float gr[E_NUM];
#pragma unroll
  for (int e = 0; e < 4; ++e) { gr[e] = g0[e]; gr[e + 4] = g1[e]; }
  if (isbf) {
    const unsigned short* bu = (const unsigned short*)biasv;
#pragma unroll
    for (int e = 0; e < E_NUM; ++e) {
      ushort8v bv = *(const ushort8v*)&bu[(size_t)e * O_DIM + o];
#pragma unroll
      for (int j = 0; j < 8; ++j) s[j] += gr[e] * bfu2f(bv[j]);
    }
  } else {
    const float* bf_ = (const float*)biasv;
#pragma unroll
    for (int e = 0; e < E_NUM; ++e) {
      f32x4 lo = *(const f32x4*)&bf_[(size_t)e * O_DIM + o];
      f32x4 hi = *(const f32x4*)&bf_[(size_t)e * O_DIM + o + 4];
#pragma unroll
      for (int j = 0; j < 4; ++j) {
        s[j]     += gr[e] * lo[j];
        s[j + 4] += gr[e] * hi[j];
      }
    }
  }
  if (isbf) {
    ushort8v pk;
#pragma unroll
    for (int j = 0; j < 8; ++j) pk[j] = f2bf(s[j]);
    *(ushort8v*)&((unsigned short*)outv)[(size_t)b * O_DIM + o] = pk;
  } else {
    float* of = (float*)outv + (size_t)b * O_DIM + o;
    f32x4 lo, hi;
#pragma unroll
    for (int j = 0; j < 4; ++j) { lo[j] = s[j]; hi[j] = s[j + 4]; }
    *(f32x4*)of = lo;
    *(f32x4*)(of + 4) = hi;
  }
}

extern "C" void kernel_launch(void* const* d_in, const int* in_sizes, int n_in,
                              void* d_out, int out_size, void* d_ws, size_t ws_size,
                              hipStream_t stream) {
  (void)in_sizes; (void)n_in; (void)out_size;
  const void* x    = d_in[0];
  const void* cond = d_in[1];
  const void* w    = d_in[2];
  const void* bias = d_in[3];
  const void* g_w1 = d_in[4];
  const void* g_b1 = d_in[5];
  const void* g_w2 = d_in[6];
  const void* g_b2 = d_in[7];

  const size_t goff  = 1024;
  const size_t wtoff = goff + (size_t)B_ROWS * E_NUM * 4;         // +128KB
  const size_t xboff = wtoff + (size_t)E_NUM * I_DIM * O_DIM * 2; // +16MB
  const size_t poff  = xboff + (size_t)B_ROWS * I_DIM * 2;        // +8MB
  const size_t slab  = (size_t)B_ROWS * O_DIM * 2;                // 8MB (f16)

  int KS = 4;
  while (KS > 1 && poff + (size_t)KS * slab > ws_size) KS >>= 1;
  const int EPB = E_NUM / KS;

  int*   flag = (int*)d_ws;
  float* g    = (float*)((char*)d_ws + goff);
  unsigned short* wt = (unsigned short*)((char*)d_ws + wtoff);
  unsigned short* xbb = (unsigned short*)((char*)d_ws + xboff);
  _Float16* pbuf = (_Float16*)((char*)d_ws + poff);

  k_detect<<<1, 128, 0, stream>>>((const unsigned short*)x, flag);
  k_prep<<<4112, 256, 0, stream>>>(x, cond, w, g_w1, g_b1, g_w2, g_b2, flag,
                                   xbb, wt, g);
  k_moe_gemm<<<KS * MT * NT, 512, 0, stream>>>(x, xbb, wt, g, flag, pbuf, EPB);
  k_combine<<<B_ROWS * O_DIM / 8 / 256, 256, 0, stream>>>(pbuf, g, bias, flag,
                                                          d_out, KS);
}